// Round 1
// baseline (839.801 us; speedup 1.0000x reference)
//
#include <hip/hip_runtime.h>
#include <math.h>

#define NB_B 512
#define NE 100000
#define DD 200
#define CC 32
#define FCIN 10368   // 32*18*18
#define HW 324       // 18*18
#define BNEPS 1e-5f

// dacc (double) slots:
// 0: bn0 sum, 1: bn0 sumsq (also l2 for h_e+r_e)
// 2..33: bn1 per-channel sum, 34..65: bn1 per-channel sumsq
// 66: conv_w sumsq, 67: fc_w sumsq
// 68: softplus sum, 69: scores sum, 70: pos-scores sum

static __device__ __forceinline__ float blk_reduce(float v, volatile float* sbuf) {
  for (int o = 32; o > 0; o >>= 1) v += __shfl_down(v, o, 64);
  int lane = threadIdx.x & 63, wid = threadIdx.x >> 6;
  if (lane == 0) sbuf[wid] = v;
  __syncthreads();
  float r = 0.f;
  int nw = (blockDim.x + 63) >> 6;
  if ((int)threadIdx.x < nw) r = sbuf[threadIdx.x];
  if (threadIdx.x < 64) {
    for (int o = 32; o > 0; o >>= 1) r += __shfl_down(r, o, 64);
  }
  __syncthreads();
  return r;  // valid on thread 0
}

// K1: gather h/r embeddings -> x0 [512 x 400]; bn0 sum/sumsq (sumsq doubles as embed L2)
__global__ void k_gather(const float* __restrict__ ent, const float* __restrict__ rel,
                         const int* __restrict__ h, const int* __restrict__ r,
                         float* __restrict__ x0, double* dacc) {
  int b = blockIdx.x;
  int hi = h[b], ri = r[b];
  float s = 0.f, sq = 0.f;
  for (int i = threadIdx.x; i < 400; i += blockDim.x) {
    float v = (i < 200) ? ent[(long)hi * DD + i] : rel[(long)ri * DD + (i - 200)];
    x0[b * 400 + i] = v;
    s += v; sq += v * v;
  }
  __shared__ float sbuf[8];
  float ts = blk_reduce(s, sbuf);
  float tq = blk_reduce(sq, sbuf);
  if (threadIdx.x == 0) {
    atomicAdd(&dacc[0], (double)ts);
    atomicAdd(&dacc[1], (double)tq);
  }
}

// K2: bn0 + conv3x3 + conv_b -> y [512 x 10368] (layout c*324+oh*18+ow); bn1 stats
__global__ __launch_bounds__(256) void k_conv(const float* __restrict__ x0,
                       const float* __restrict__ convw, const float* __restrict__ convb,
                       const float* __restrict__ g0, const float* __restrict__ b0,
                       float* __restrict__ y, double* dacc) {
  __shared__ float xs[400], wsm[288], cbs[32], ssum[32], ssq[32];
  __shared__ float a0s, s0s;
  int b = blockIdx.x, t = threadIdx.x;
  for (int i = t; i < 400; i += 256) xs[i] = x0[b * 400 + i];
  for (int i = t; i < 288; i += 256) wsm[i] = convw[i];
  if (t < 32) { cbs[t] = convb[t]; ssum[t] = 0.f; ssq[t] = 0.f; }
  if (t == 0) {
    double m = dacc[0] / 204800.0;
    double v = dacc[1] / 204800.0 - m * m;
    float a = g0[0] * rsqrtf((float)v + BNEPS);
    a0s = a; s0s = b0[0] - (float)m * a;
  }
  __syncthreads();
  float a0 = a0s, s0 = s0s;
  for (int i = t; i < 400; i += 256) xs[i] = a0 * xs[i] + s0;
  __syncthreads();
  for (int o = t; o < FCIN; o += 256) {
    int c = o / HW, rem = o - c * HW;
    int oh = rem / 18, ow = rem - oh * 18;
    const float* w = &wsm[c * 9];
    const float* xp = &xs[oh * 20 + ow];
    float acc = cbs[c];
    acc += xp[0] * w[0] + xp[1] * w[1] + xp[2] * w[2]
         + xp[20] * w[3] + xp[21] * w[4] + xp[22] * w[5]
         + xp[40] * w[6] + xp[41] * w[7] + xp[42] * w[8];
    y[(long)b * FCIN + o] = acc;
    atomicAdd(&ssum[c], acc);
    atomicAdd(&ssq[c], acc * acc);
  }
  __syncthreads();
  if (t < 32) {
    atomicAdd(&dacc[2 + t], (double)ssum[t]);
    atomicAdd(&dacc[34 + t], (double)ssq[t]);
  }
}

// K3: finalize bn1 scale/shift; conv_w L2
__global__ void k_stats1(const float* __restrict__ g1, const float* __restrict__ b1,
                         const float* __restrict__ convw,
                         float* __restrict__ a1, float* __restrict__ sh1, double* dacc) {
  int t = threadIdx.x;  // 64 threads
  if (t < 32) {
    double cnt = 512.0 * 324.0;
    double m = dacc[2 + t] / cnt, v = dacc[34 + t] / cnt - m * m;
    float a = g1[t] * rsqrtf((float)v + BNEPS);
    a1[t] = a; sh1[t] = b1[t] - (float)m * a;
  }
  float sq = 0.f;
  for (int i = t; i < 288; i += 64) { float w = convw[i]; sq += w * w; }
  for (int o = 32; o > 0; o >>= 1) sq += __shfl_down(sq, o, 64);
  if (t == 0) dacc[66] = (double)sq;
}

// K3b: fc_w sum of squares (L2)
__global__ void k_fcsq(const float* __restrict__ fcw, double* dacc) {
  float sq = 0.f;
  long n = (long)DD * FCIN;
  for (long i = (long)blockIdx.x * blockDim.x + threadIdx.x; i < n;
       i += (long)gridDim.x * blockDim.x) {
    float w = fcw[i]; sq += w * w;
  }
  __shared__ float sbuf[8];
  float tq = blk_reduce(sq, sbuf);
  if (threadIdx.x == 0) atomicAdd(&dacc[67], (double)tq);
}

// K4: FC GEMM  Cfc[b,d] += sum_k relu(bn1(y[b,k])) * fcw[d,k]   (k-split, atomic accumulate)
__global__ __launch_bounds__(256) void k_fc(const float* __restrict__ y,
                      const float* __restrict__ fcw,
                      const float* __restrict__ a1, const float* __restrict__ sh1,
                      float* __restrict__ Cfc) {
  __shared__ float a_s[8 * 64], b_s[8 * 64];
  int t = threadIdx.x;
  int n0 = blockIdx.x * 64;       // d tile
  int m0 = blockIdx.y * 64;       // b tile
  int kbase = blockIdx.z * 1296;  // 10368 / 8
  int tx = t & 15, ty = t >> 4;
  float acc[4][4] = {};
  for (int kc = kbase; kc < kbase + 1296; kc += 8) {
    __syncthreads();
    {
      int ei = t * 2; int m = ei >> 3, kcol = ei & 7;
      float2 v = *(const float2*)&y[(long)(m0 + m) * FCIN + kc + kcol];
      int k0g = kc + kcol, k1g = k0g + 1;
      int c0 = k0g / HW, c1 = k1g / HW;
      a_s[kcol * 64 + m]       = fmaxf(0.f, a1[c0] * v.x + sh1[c0]);
      a_s[(kcol + 1) * 64 + m] = fmaxf(0.f, a1[c1] * v.y + sh1[c1]);
      int d = n0 + m;
      float2 w;
      if (d < DD) w = *(const float2*)&fcw[(long)d * FCIN + kc + kcol];
      else { w.x = 0.f; w.y = 0.f; }
      b_s[kcol * 64 + m]       = w.x;
      b_s[(kcol + 1) * 64 + m] = w.y;
    }
    __syncthreads();
#pragma unroll
    for (int kk = 0; kk < 8; kk++) {
      float av[4], bv[4];
#pragma unroll
      for (int j = 0; j < 4; j++) bv[j] = b_s[kk * 64 + tx * 4 + j];
#pragma unroll
      for (int i = 0; i < 4; i++) av[i] = a_s[kk * 64 + ty * 4 + i];
#pragma unroll
      for (int i = 0; i < 4; i++)
#pragma unroll
        for (int j = 0; j < 4; j++) acc[i][j] += av[i] * bv[j];
    }
  }
  for (int i = 0; i < 4; i++) {
    int m = m0 + ty * 4 + i;
    for (int j = 0; j < 4; j++) {
      int d = n0 + tx * 4 + j;
      if (d < DD) atomicAdd(&Cfc[m * DD + d], acc[i][j]);
    }
  }
}

// K5: bn2 stats per feature -> a2/b2c
__global__ void k_bn2stats(const float* __restrict__ Cfc, const float* __restrict__ fcb,
                           const float* __restrict__ g2, const float* __restrict__ b2,
                           float* __restrict__ a2, float* __restrict__ b2c) {
  int d = blockIdx.x, lane = threadIdx.x;  // 64 threads
  float s = 0.f, sq = 0.f;
  for (int b = lane; b < NB_B; b += 64) {
    float v = Cfc[b * DD + d] + fcb[d];
    s += v; sq += v * v;
  }
  for (int o = 32; o > 0; o >>= 1) { s += __shfl_down(s, o, 64); sq += __shfl_down(sq, o, 64); }
  if (lane == 0) {
    float m = s / 512.f, v = sq / 512.f - m * m;
    float a = g2[d] * rsqrtf(v + BNEPS);
    a2[d] = a; b2c[d] = b2[d] - m * a;
  }
}

// K6: x_final = leaky_relu(bn2(fc))
__global__ void k_xfinal(const float* __restrict__ Cfc, const float* __restrict__ fcb,
                         const float* __restrict__ a2, const float* __restrict__ b2c,
                         float* __restrict__ xf) {
  int idx = blockIdx.x * 256 + threadIdx.x;
  if (idx < NB_B * DD) {
    int d = idx % DD;
    float v = Cfc[idx] + fcb[d];
    float xv = a2[d] * v + b2c[d];
    xf[idx] = xv >= 0.f ? xv : 0.01f * xv;
  }
}

// K7: sum_b scores[b, pos_t[b]]
__global__ void k_pos(const float* __restrict__ xf, const float* __restrict__ ent,
                      const float* __restrict__ bias, const int* __restrict__ pos,
                      double* dacc) {
  int b = blockIdx.x, lane = threadIdx.x;  // 64 threads
  int e = pos[b];
  float s = 0.f;
  for (int k = lane; k < DD; k += 64) s += xf[b * DD + k] * ent[(long)e * DD + k];
  for (int o = 32; o > 0; o >>= 1) s += __shfl_down(s, o, 64);
  if (lane == 0) atomicAdd(&dacc[70], (double)(s + bias[e]));
}

// K8: scores GEMM (512x100000, K=200) with fused softplus/sum loss epilogue
__global__ __launch_bounds__(256) void k_scores(const float* __restrict__ xf,
                          const float* __restrict__ ent, const float* __restrict__ bias,
                          double* dacc) {
  __shared__ float es[8 * 64], xs[8 * 128];
  int t = threadIdx.x;
  int n0 = blockIdx.x * 64;    // entity tile
  int m0 = blockIdx.y * 128;   // batch tile
  int tx = t & 15, ty = t >> 4;
  float acc[8][4] = {};
  for (int kc = 0; kc < DD; kc += 8) {  // 25 chunks exactly
    __syncthreads();
    {
      int ei = t * 2; int e = ei >> 3, kcol = ei & 7;
      int eg = n0 + e;
      float2 v;
      if (eg < NE) v = *(const float2*)&ent[(long)eg * DD + kc + kcol];
      else { v.x = 0.f; v.y = 0.f; }
      es[kcol * 64 + e]       = v.x;
      es[(kcol + 1) * 64 + e] = v.y;
      int xi = t * 4; int m = xi >> 3, kc2 = xi & 7;
      float4 w = *(const float4*)&xf[(long)(m0 + m) * DD + kc + kc2];
      xs[kc2 * 128 + m]       = w.x;
      xs[(kc2 + 1) * 128 + m] = w.y;
      xs[(kc2 + 2) * 128 + m] = w.z;
      xs[(kc2 + 3) * 128 + m] = w.w;
    }
    __syncthreads();
#pragma unroll
    for (int kk = 0; kk < 8; kk++) {
      float av[4], bv[8];
#pragma unroll
      for (int j = 0; j < 4; j++) av[j] = es[kk * 64 + tx * 4 + j];
#pragma unroll
      for (int i = 0; i < 8; i++) bv[i] = xs[kk * 128 + ty * 8 + i];
#pragma unroll
      for (int i = 0; i < 8; i++)
#pragma unroll
        for (int j = 0; j < 4; j++) acc[i][j] += bv[i] * av[j];
    }
  }
  float sp = 0.f, ss = 0.f;
#pragma unroll
  for (int j = 0; j < 4; j++) {
    int eg = n0 + tx * 4 + j;
    if (eg < NE) {
      float be = bias[eg];
#pragma unroll
      for (int i = 0; i < 8; i++) {
        float s = acc[i][j] + be;
        sp += fmaxf(s, 0.f) + log1pf(expf(-fabsf(s)));
        ss += s;
      }
    }
  }
  __shared__ float sbuf[8];
  float tsp = blk_reduce(sp, sbuf);
  float tss = blk_reduce(ss, sbuf);
  if (t == 0) {
    atomicAdd(&dacc[68], (double)tsp);
    atomicAdd(&dacc[69], (double)tss);
  }
}

// K9: final scalar
__global__ void k_final(const double* dacc, float* out) {
  double SP = dacc[68], S2 = dacc[69], S3 = dacc[70];
  double xy = S2 / (double)NE + 0.9 * S3;
  double kg = (SP - xy) / ((double)NB_B * (double)NE);
  double l2 = dacc[1] / 204800.0 + dacc[66] / 576.0 + dacc[67] / 400.0;
  out[0] = (float)(kg + 1e-5 * l2);
}

extern "C" void kernel_launch(void* const* d_in, const int* in_sizes, int n_in,
                              void* d_out, int out_size, void* d_ws, size_t ws_size,
                              hipStream_t stream) {
  const float* ent   = (const float*)d_in[0];
  const float* rel   = (const float*)d_in[1];
  const float* convw = (const float*)d_in[2];
  const float* convb = (const float*)d_in[3];
  const float* fcw   = (const float*)d_in[4];
  const float* fcb   = (const float*)d_in[5];
  const float* bias  = (const float*)d_in[6];
  const float* g0    = (const float*)d_in[7];
  const float* b0    = (const float*)d_in[8];
  const float* g1    = (const float*)d_in[9];
  const float* b1    = (const float*)d_in[10];
  const float* g2    = (const float*)d_in[11];
  const float* b2    = (const float*)d_in[12];
  const int*   h     = (const int*)d_in[13];
  const int*   r     = (const int*)d_in[14];
  const int*   pos   = (const int*)d_in[15];

  char* ws = (char*)d_ws;
  double* dacc = (double*)(ws + 0);                       // 8 KB
  float* a1  = (float*)(ws + 16384);                      // 32
  float* sh1 = (float*)(ws + 16384 + 128);                // 32
  float* a2  = (float*)(ws + 16384 + 256);                // 200
  float* b2c = (float*)(ws + 16384 + 1056);               // 200
  float* x0  = (float*)(ws + 32768);                      // 512*400
  float* Cfc = (float*)(ws + 32768 + 819200);             // 512*200
  float* xf  = (float*)(ws + 32768 + 819200 + 409600);    // 512*200
  float* y   = (float*)(ws + 32768 + 819200 + 409600 + 409600);  // 512*10368

  hipMemsetAsync(dacc, 0, 8192, stream);
  hipMemsetAsync(Cfc, 0, 409600, stream);

  k_gather<<<512, 256, 0, stream>>>(ent, rel, h, r, x0, dacc);
  k_conv<<<512, 256, 0, stream>>>(x0, convw, convb, g0, b0, y, dacc);
  k_stats1<<<1, 64, 0, stream>>>(g1, b1, convw, a1, sh1, dacc);
  k_fcsq<<<256, 256, 0, stream>>>(fcw, dacc);
  k_fc<<<dim3(4, 8, 8), 256, 0, stream>>>(y, fcw, a1, sh1, Cfc);
  k_bn2stats<<<200, 64, 0, stream>>>(Cfc, fcb, g2, b2, a2, b2c);
  k_xfinal<<<400, 256, 0, stream>>>(Cfc, fcb, a2, b2c, xf);
  k_pos<<<512, 64, 0, stream>>>(xf, ent, bias, pos, dacc);
  k_scores<<<dim3(1563, 4), 256, 0, stream>>>(xf, ent, bias, dacc);
  k_final<<<1, 1, 0, stream>>>(dacc, (float*)d_out);
}

// Round 2
// 463.523 us; speedup vs baseline: 1.8118x; 1.8118x over previous
//
#include <hip/hip_runtime.h>
#include <math.h>

#define NB_B 512
#define NE 100000
#define DD 200
#define CC 32
#define FCIN 10368   // 32*18*18
#define HW 324       // 18*18
#define BNEPS 1e-5f
#define KP 224       // K padded to multiple of 32 for MFMA

typedef __attribute__((ext_vector_type(8))) short short8;   // 8 bf16 = 4 VGPRs
typedef __attribute__((ext_vector_type(4))) float floatx4;  // MFMA acc

// dacc (double) slots:
// 0: bn0 sum, 1: bn0 sumsq (also l2 for h_e+r_e)
// 2..33: bn1 per-channel sum, 34..65: bn1 per-channel sumsq
// 66: conv_w sumsq, 67: fc_w sumsq
// 68: softplus sum, 69: scores sum, 70: pos-scores sum

static __device__ __forceinline__ float blk_reduce(float v, volatile float* sbuf) {
  for (int o = 32; o > 0; o >>= 1) v += __shfl_down(v, o, 64);
  int lane = threadIdx.x & 63, wid = threadIdx.x >> 6;
  if (lane == 0) sbuf[wid] = v;
  __syncthreads();
  float r = 0.f;
  int nw = (blockDim.x + 63) >> 6;
  if ((int)threadIdx.x < nw) r = sbuf[threadIdx.x];
  if (threadIdx.x < 64) {
    for (int o = 32; o > 0; o >>= 1) r += __shfl_down(r, o, 64);
  }
  __syncthreads();
  return r;  // valid on thread 0
}

static __device__ __forceinline__ unsigned short f32_to_bf16(float f) {
  unsigned int u = __float_as_uint(f);
  u += 0x7fffu + ((u >> 16) & 1u);  // round-to-nearest-even
  return (unsigned short)(u >> 16);
}

// K1: gather h/r embeddings -> x0 [512 x 400]; bn0 sum/sumsq (sumsq doubles as embed L2)
__global__ void k_gather(const float* __restrict__ ent, const float* __restrict__ rel,
                         const int* __restrict__ h, const int* __restrict__ r,
                         float* __restrict__ x0, double* dacc) {
  int b = blockIdx.x;
  int hi = h[b], ri = r[b];
  float s = 0.f, sq = 0.f;
  for (int i = threadIdx.x; i < 400; i += blockDim.x) {
    float v = (i < 200) ? ent[(long)hi * DD + i] : rel[(long)ri * DD + (i - 200)];
    x0[b * 400 + i] = v;
    s += v; sq += v * v;
  }
  __shared__ float sbuf[8];
  float ts = blk_reduce(s, sbuf);
  float tq = blk_reduce(sq, sbuf);
  if (threadIdx.x == 0) {
    atomicAdd(&dacc[0], (double)ts);
    atomicAdd(&dacc[1], (double)tq);
  }
}

// K1b: convert entity_w f32 -> bf16 with K padded 200->224 (zeros)
__global__ __launch_bounds__(256) void k_cvt_ent(const float* __restrict__ ent,
                                                 unsigned short* __restrict__ entb) {
  int i4 = blockIdx.x * 256 + threadIdx.x;   // 0 .. 5,599,999  (100000*56)
  int row = i4 / 56;
  int c4 = (i4 - row * 56) * 4;
  ushort4 o;
  if (c4 < 200) {
    const float4 v = *(const float4*)&ent[(long)row * DD + c4];
    o.x = f32_to_bf16(v.x); o.y = f32_to_bf16(v.y);
    o.z = f32_to_bf16(v.z); o.w = f32_to_bf16(v.w);
  } else {
    o.x = 0; o.y = 0; o.z = 0; o.w = 0;
  }
  *(ushort4*)&entb[(long)row * KP + c4] = o;
}

// K2: bn0 + conv3x3 + conv_b -> y [512 x 10368]; bn1 stats via per-channel lane groups
__global__ __launch_bounds__(256) void k_conv(const float* __restrict__ x0,
                       const float* __restrict__ convw, const float* __restrict__ convb,
                       const float* __restrict__ g0, const float* __restrict__ b0,
                       float* __restrict__ y, double* dacc) {
  __shared__ float xs[400], wsm[288], cbs[32], ssum[32], ssq[32];
  __shared__ float a0s, s0s;
  int b = blockIdx.x, t = threadIdx.x;
  for (int i = t; i < 400; i += 256) xs[i] = x0[b * 400 + i];
  for (int i = t; i < 288; i += 256) wsm[i] = convw[i];
  if (t < 32) cbs[t] = convb[t];
  if (t == 0) {
    double m = dacc[0] / 204800.0;
    double v = dacc[1] / 204800.0 - m * m;
    float a = g0[0] * rsqrtf((float)v + BNEPS);
    a0s = a; s0s = b0[0] - (float)m * a;
  }
  __syncthreads();
  float a0 = a0s, s0 = s0s;
  for (int i = t; i < 400; i += 256) xs[i] = a0 * xs[i] + s0;
  __syncthreads();
  // each group of 8 lanes handles one channel c = t>>3
  int c = t >> 3, sub = t & 7;
  const float* w = &wsm[c * 9];
  float cb = cbs[c];
  float s = 0.f, sq = 0.f;
  for (int e = sub; e < HW; e += 8) {
    int oh = e / 18, ow = e - oh * 18;
    const float* xp = &xs[oh * 20 + ow];
    float acc = cb
       + xp[0] * w[0] + xp[1] * w[1] + xp[2] * w[2]
       + xp[20] * w[3] + xp[21] * w[4] + xp[22] * w[5]
       + xp[40] * w[6] + xp[41] * w[7] + xp[42] * w[8];
    y[(long)b * FCIN + c * HW + e] = acc;
    s += acc; sq += acc * acc;
  }
  s += __shfl_xor(s, 1, 64); sq += __shfl_xor(sq, 1, 64);
  s += __shfl_xor(s, 2, 64); sq += __shfl_xor(sq, 2, 64);
  s += __shfl_xor(s, 4, 64); sq += __shfl_xor(sq, 4, 64);
  if (sub == 0) { ssum[c] = s; ssq[c] = sq; }
  __syncthreads();
  if (t < 32) {
    atomicAdd(&dacc[2 + t], (double)ssum[t]);
    atomicAdd(&dacc[34 + t], (double)ssq[t]);
  }
}

// K3: finalize bn1 scale/shift; conv_w L2
__global__ void k_stats1(const float* __restrict__ g1, const float* __restrict__ b1,
                         const float* __restrict__ convw,
                         float* __restrict__ a1, float* __restrict__ sh1, double* dacc) {
  int t = threadIdx.x;  // 64 threads
  if (t < 32) {
    double cnt = 512.0 * 324.0;
    double m = dacc[2 + t] / cnt, v = dacc[34 + t] / cnt - m * m;
    float a = g1[t] * rsqrtf((float)v + BNEPS);
    a1[t] = a; sh1[t] = b1[t] - (float)m * a;
  }
  float sq = 0.f;
  for (int i = t; i < 288; i += 64) { float w = convw[i]; sq += w * w; }
  for (int o = 32; o > 0; o >>= 1) sq += __shfl_down(sq, o, 64);
  if (t == 0) dacc[66] = (double)sq;
}

// K3b: fc_w sum of squares (L2)
__global__ void k_fcsq(const float* __restrict__ fcw, double* dacc) {
  float sq = 0.f;
  long n = (long)DD * FCIN;
  for (long i = (long)blockIdx.x * blockDim.x + threadIdx.x; i < n;
       i += (long)gridDim.x * blockDim.x) {
    float w = fcw[i]; sq += w * w;
  }
  __shared__ float sbuf[8];
  float tq = blk_reduce(sq, sbuf);
  if (threadIdx.x == 0) atomicAdd(&dacc[67], (double)tq);
}

// K4: FC GEMM  Cfc[b,d] += sum_k relu(bn1(y[b,k])) * fcw[d,k]   (k-split, atomic accumulate)
__global__ __launch_bounds__(256) void k_fc(const float* __restrict__ y,
                      const float* __restrict__ fcw,
                      const float* __restrict__ a1, const float* __restrict__ sh1,
                      float* __restrict__ Cfc) {
  __shared__ float a_s[8 * 64], b_s[8 * 64];
  int t = threadIdx.x;
  int n0 = blockIdx.x * 64;       // d tile
  int m0 = blockIdx.y * 64;       // b tile
  int kbase = blockIdx.z * 1296;  // 10368 / 8
  int tx = t & 15, ty = t >> 4;
  float acc[4][4] = {};
  for (int kc = kbase; kc < kbase + 1296; kc += 8) {
    __syncthreads();
    {
      int ei = t * 2; int m = ei >> 3, kcol = ei & 7;
      float2 v = *(const float2*)&y[(long)(m0 + m) * FCIN + kc + kcol];
      int k0g = kc + kcol, k1g = k0g + 1;
      int c0 = k0g / HW, c1 = k1g / HW;
      a_s[kcol * 64 + m]       = fmaxf(0.f, a1[c0] * v.x + sh1[c0]);
      a_s[(kcol + 1) * 64 + m] = fmaxf(0.f, a1[c1] * v.y + sh1[c1]);
      int d = n0 + m;
      float2 w;
      if (d < DD) w = *(const float2*)&fcw[(long)d * FCIN + kc + kcol];
      else { w.x = 0.f; w.y = 0.f; }
      b_s[kcol * 64 + m]       = w.x;
      b_s[(kcol + 1) * 64 + m] = w.y;
    }
    __syncthreads();
#pragma unroll
    for (int kk = 0; kk < 8; kk++) {
      float av[4], bv[4];
#pragma unroll
      for (int j = 0; j < 4; j++) bv[j] = b_s[kk * 64 + tx * 4 + j];
#pragma unroll
      for (int i = 0; i < 4; i++) av[i] = a_s[kk * 64 + ty * 4 + i];
#pragma unroll
      for (int i = 0; i < 4; i++)
#pragma unroll
        for (int j = 0; j < 4; j++) acc[i][j] += av[i] * bv[j];
    }
  }
  for (int i = 0; i < 4; i++) {
    int m = m0 + ty * 4 + i;
    for (int j = 0; j < 4; j++) {
      int d = n0 + tx * 4 + j;
      if (d < DD) atomicAdd(&Cfc[m * DD + d], acc[i][j]);
    }
  }
}

// K5: bn2 stats per feature -> a2/b2c
__global__ void k_bn2stats(const float* __restrict__ Cfc, const float* __restrict__ fcb,
                           const float* __restrict__ g2, const float* __restrict__ b2,
                           float* __restrict__ a2, float* __restrict__ b2c) {
  int d = blockIdx.x, lane = threadIdx.x;  // 64 threads
  float s = 0.f, sq = 0.f;
  for (int b = lane; b < NB_B; b += 64) {
    float v = Cfc[b * DD + d] + fcb[d];
    s += v; sq += v * v;
  }
  for (int o = 32; o > 0; o >>= 1) { s += __shfl_down(s, o, 64); sq += __shfl_down(sq, o, 64); }
  if (lane == 0) {
    float m = s / 512.f, v = sq / 512.f - m * m;
    float a = g2[d] * rsqrtf(v + BNEPS);
    a2[d] = a; b2c[d] = b2[d] - m * a;
  }
}

// K6: x_final = leaky_relu(bn2(fc)); write f32 (for k_pos) and bf16 padded (for MFMA)
__global__ void k_xfinal(const float* __restrict__ Cfc, const float* __restrict__ fcb,
                         const float* __restrict__ a2, const float* __restrict__ b2c,
                         float* __restrict__ xf, unsigned short* __restrict__ xfb) {
  int idx = blockIdx.x * 256 + threadIdx.x;  // 512*224
  int row = idx / KP, col = idx - row * KP;
  if (col < DD) {
    float v = Cfc[row * DD + col] + fcb[col];
    float xv = a2[col] * v + b2c[col];
    xv = xv >= 0.f ? xv : 0.01f * xv;
    xf[row * DD + col] = xv;
    xfb[idx] = f32_to_bf16(xv);
  } else {
    xfb[idx] = 0;
  }
}

// K7: sum_b scores[b, pos_t[b]]  (f32 path, high accuracy)
__global__ void k_pos(const float* __restrict__ xf, const float* __restrict__ ent,
                      const float* __restrict__ bias, const int* __restrict__ pos,
                      double* dacc) {
  int b = blockIdx.x, lane = threadIdx.x;  // 64 threads
  int e = pos[b];
  float s = 0.f;
  for (int k = lane; k < DD; k += 64) s += xf[b * DD + k] * ent[(long)e * DD + k];
  for (int o = 32; o > 0; o >>= 1) s += __shfl_down(s, o, 64);
  if (lane == 0) atomicAdd(&dacc[70], (double)(s + bias[e]));
}

// K8: scores GEMM via bf16 MFMA: D[e,b] = sum_k entb[e,k]*xfb[b,k]; fused loss epilogue.
// Block tile: 64 entities (M) x 256 batch (N); 4 waves, each 64x64 (4x4 MFMA tiles).
__global__ __launch_bounds__(256) void k_scores_mfma(
    const unsigned short* __restrict__ entb,  // [NE][KP] bf16 bits
    const unsigned short* __restrict__ xfb,   // [512][KP] bf16 bits
    const float* __restrict__ bias, double* dacc) {
  __shared__ __align__(16) unsigned short xs[256 * 40];  // 256 rows x 32 k, stride 40
  __shared__ float sbuf[8];
  int t = threadIdx.x;
  int e0 = blockIdx.x * 64;
  int n0 = blockIdx.y * 256;
  int wv = t >> 6, lane = t & 63;
  int quad = lane >> 4, lr = lane & 15;

  floatx4 acc[4][4];
#pragma unroll
  for (int i = 0; i < 4; i++)
#pragma unroll
    for (int j = 0; j < 4; j++) acc[i][j] = (floatx4){0.f, 0.f, 0.f, 0.f};

  for (int kc = 0; kc < KP; kc += 32) {  // 7 chunks
    __syncthreads();
    {  // stage xf chunk: thread t copies row n0+t, 32 bf16 (64B)
      const uint4* src = (const uint4*)(xfb + (size_t)(n0 + t) * KP + kc);
      uint4* dst = (uint4*)(xs + t * 40);
      dst[0] = src[0]; dst[1] = src[1]; dst[2] = src[2]; dst[3] = src[3];
    }
    __syncthreads();
    short8 af[4];
#pragma unroll
    for (int mi = 0; mi < 4; mi++) {
      int e = e0 + mi * 16 + lr;
      if (e >= NE) e = NE - 1;  // clamp; excluded in epilogue
      af[mi] = *(const short8*)(entb + (size_t)e * KP + kc + quad * 8);
    }
#pragma unroll
    for (int ni = 0; ni < 4; ni++) {
      short8 bf = *(const short8*)(xs + (wv * 64 + ni * 16 + lr) * 40 + quad * 8);
#pragma unroll
      for (int mi = 0; mi < 4; mi++) {
        acc[mi][ni] = __builtin_amdgcn_mfma_f32_16x16x32_bf16(af[mi], bf, acc[mi][ni], 0, 0, 0);
      }
    }
  }

  // epilogue: D row = e0 + mi*16 + quad*4 + reg, col = n0 + wv*64 + ni*16 + lr
  float sp = 0.f, ss = 0.f;
#pragma unroll
  for (int mi = 0; mi < 4; mi++) {
    int ebase = e0 + mi * 16 + quad * 4;
    float b4[4];
    if (ebase + 3 < NE) {
      float4 bv = *(const float4*)&bias[ebase];
      b4[0] = bv.x; b4[1] = bv.y; b4[2] = bv.z; b4[3] = bv.w;
    } else {
#pragma unroll
      for (int rg = 0; rg < 4; rg++) b4[rg] = (ebase + rg < NE) ? bias[ebase + rg] : 0.f;
    }
#pragma unroll
    for (int ni = 0; ni < 4; ni++) {
#pragma unroll
      for (int rg = 0; rg < 4; rg++) {
        if (ebase + rg < NE) {
          float s = acc[mi][ni][rg] + b4[rg];
          sp += fmaxf(s, 0.f) + __logf(1.f + __expf(-fabsf(s)));
          ss += s;
        }
      }
    }
  }
  float tsp = blk_reduce(sp, sbuf);
  float tss = blk_reduce(ss, sbuf);
  if (t == 0) {
    atomicAdd(&dacc[68], (double)tsp);
    atomicAdd(&dacc[69], (double)tss);
  }
}

// K9: final scalar
__global__ void k_final(const double* dacc, float* out) {
  double SP = dacc[68], S2 = dacc[69], S3 = dacc[70];
  double xy = S2 / (double)NE + 0.9 * S3;
  double kg = (SP - xy) / ((double)NB_B * (double)NE);
  double l2 = dacc[1] / 204800.0 + dacc[66] / 576.0 + dacc[67] / 400.0;
  out[0] = (float)(kg + 1e-5 * l2);
}

extern "C" void kernel_launch(void* const* d_in, const int* in_sizes, int n_in,
                              void* d_out, int out_size, void* d_ws, size_t ws_size,
                              hipStream_t stream) {
  const float* ent   = (const float*)d_in[0];
  const float* rel   = (const float*)d_in[1];
  const float* convw = (const float*)d_in[2];
  const float* convb = (const float*)d_in[3];
  const float* fcw   = (const float*)d_in[4];
  const float* fcb   = (const float*)d_in[5];
  const float* bias  = (const float*)d_in[6];
  const float* g0    = (const float*)d_in[7];
  const float* b0    = (const float*)d_in[8];
  const float* g1    = (const float*)d_in[9];
  const float* b1    = (const float*)d_in[10];
  const float* g2    = (const float*)d_in[11];
  const float* b2    = (const float*)d_in[12];
  const int*   h     = (const int*)d_in[13];
  const int*   r     = (const int*)d_in[14];
  const int*   pos   = (const int*)d_in[15];

  char* ws = (char*)d_ws;
  double* dacc = (double*)(ws + 0);                       // 8 KB
  float* a1  = (float*)(ws + 16384);                      // 32
  float* sh1 = (float*)(ws + 16384 + 128);                // 32
  float* a2  = (float*)(ws + 16384 + 256);                // 200
  float* b2c = (float*)(ws + 16384 + 1056);               // 200
  float* x0  = (float*)(ws + 32768);                      // 512*400          (819200 B)
  float* Cfc = (float*)(ws + 851968);                     // 512*200          (409600 B)
  float* xf  = (float*)(ws + 1261568);                    // 512*200          (409600 B)
  float* y   = (float*)(ws + 1671168);                    // 512*10368        (21233664 B)
  unsigned short* xfb  = (unsigned short*)(ws + 22904832);  // 512*224 bf16   (229376 B)
  unsigned short* entb = (unsigned short*)(ws + 23134208);  // 100000*224 bf16 (44800000 B)

  hipMemsetAsync(dacc, 0, 8192, stream);
  hipMemsetAsync(Cfc, 0, 409600, stream);

  k_cvt_ent<<<21875, 256, 0, stream>>>(ent, entb);
  k_gather<<<512, 256, 0, stream>>>(ent, rel, h, r, x0, dacc);
  k_conv<<<512, 256, 0, stream>>>(x0, convw, convb, g0, b0, y, dacc);
  k_stats1<<<1, 64, 0, stream>>>(g1, b1, convw, a1, sh1, dacc);
  k_fcsq<<<256, 256, 0, stream>>>(fcw, dacc);
  k_fc<<<dim3(4, 8, 8), 256, 0, stream>>>(y, fcw, a1, sh1, Cfc);
  k_bn2stats<<<200, 64, 0, stream>>>(Cfc, fcb, g2, b2, a2, b2c);
  k_xfinal<<<448, 256, 0, stream>>>(Cfc, fcb, a2, b2c, xf, xfb);
  k_pos<<<512, 64, 0, stream>>>(xf, ent, bias, pos, dacc);
  k_scores_mfma<<<dim3(1563, 2), 256, 0, stream>>>(entb, xfb, bias, dacc);
  k_final<<<1, 1, 0, stream>>>(dacc, (float*)d_out);
}

// Round 3
// 369.026 us; speedup vs baseline: 2.2757x; 1.2561x over previous
//
#include <hip/hip_runtime.h>
#include <math.h>

#define NB_B 512
#define NE 100000
#define DD 200
#define CC 32
#define FCIN 10368   // 32*18*18
#define HW 324       // 18*18
#define BNEPS 1e-5f
#define KP 224       // scores K padded to multiple of 32 for MFMA

typedef __attribute__((ext_vector_type(8))) short short8;   // 8 bf16 = 4 VGPRs
typedef __attribute__((ext_vector_type(4))) float floatx4;  // MFMA acc

// dacc (double) slots:
// 0: bn0 sum, 1: bn0 sumsq (also l2 for h_e+r_e)
// 2..33: bn1 per-channel sum, 34..65: bn1 per-channel sumsq
// 66: conv_w sumsq, 67: fc_w sumsq
// 68: softplus sum, 69: scores sum, 70: pos-scores sum

static __device__ __forceinline__ float blk_reduce(float v, volatile float* sbuf) {
  for (int o = 32; o > 0; o >>= 1) v += __shfl_down(v, o, 64);
  int lane = threadIdx.x & 63, wid = threadIdx.x >> 6;
  if (lane == 0) sbuf[wid] = v;
  __syncthreads();
  float r = 0.f;
  int nw = (blockDim.x + 63) >> 6;
  if ((int)threadIdx.x < nw) r = sbuf[threadIdx.x];
  if (threadIdx.x < 64) {
    for (int o = 32; o > 0; o >>= 1) r += __shfl_down(r, o, 64);
  }
  __syncthreads();
  return r;  // valid on thread 0
}

static __device__ __forceinline__ unsigned short f32_to_bf16(float f) {
  unsigned int u = __float_as_uint(f);
  u += 0x7fffu + ((u >> 16) & 1u);  // round-to-nearest-even
  return (unsigned short)(u >> 16);
}
static __device__ __forceinline__ float bf16_to_f32(unsigned short b) {
  return __uint_as_float(((unsigned int)b) << 16);
}

// K1: gather h/r embeddings -> x0 [512 x 400]; bn0 sum/sumsq (sumsq doubles as embed L2)
__global__ void k_gather(const float* __restrict__ ent, const float* __restrict__ rel,
                         const int* __restrict__ h, const int* __restrict__ r,
                         float* __restrict__ x0, double* dacc) {
  int b = blockIdx.x;
  int hi = h[b], ri = r[b];
  float s = 0.f, sq = 0.f;
  for (int i = threadIdx.x; i < 400; i += blockDim.x) {
    float v = (i < 200) ? ent[(long)hi * DD + i] : rel[(long)ri * DD + (i - 200)];
    x0[b * 400 + i] = v;
    s += v; sq += v * v;
  }
  __shared__ float sbuf[8];
  float ts = blk_reduce(s, sbuf);
  float tq = blk_reduce(sq, sbuf);
  if (threadIdx.x == 0) {
    atomicAdd(&dacc[0], (double)ts);
    atomicAdd(&dacc[1], (double)tq);
  }
}

// K1b: convert entity_w f32 -> bf16 with K padded 200->224 (zeros)
__global__ __launch_bounds__(256) void k_cvt_ent(const float* __restrict__ ent,
                                                 unsigned short* __restrict__ entb) {
  int i4 = blockIdx.x * 256 + threadIdx.x;   // 0 .. 5,599,999  (100000*56)
  int row = i4 / 56;
  int c4 = (i4 - row * 56) * 4;
  ushort4 o;
  if (c4 < 200) {
    const float4 v = *(const float4*)&ent[(long)row * DD + c4];
    o.x = f32_to_bf16(v.x); o.y = f32_to_bf16(v.y);
    o.z = f32_to_bf16(v.z); o.w = f32_to_bf16(v.w);
  } else {
    o.x = 0; o.y = 0; o.z = 0; o.w = 0;
  }
  *(ushort4*)&entb[(long)row * KP + c4] = o;
}

// K2: bn0 + conv3x3 + conv_b -> yb bf16 [512 x 10368] (pre-bn1); bn1 stats (f32)
__global__ __launch_bounds__(256) void k_conv(const float* __restrict__ x0,
                       const float* __restrict__ convw, const float* __restrict__ convb,
                       const float* __restrict__ g0, const float* __restrict__ b0,
                       unsigned short* __restrict__ yb, double* dacc) {
  __shared__ float xs[400], wsm[288], cbs[32], ssum[32], ssq[32];
  __shared__ float a0s, s0s;
  int b = blockIdx.x, t = threadIdx.x;
  for (int i = t; i < 400; i += 256) xs[i] = x0[b * 400 + i];
  for (int i = t; i < 288; i += 256) wsm[i] = convw[i];
  if (t < 32) cbs[t] = convb[t];
  if (t == 0) {
    double m = dacc[0] / 204800.0;
    double v = dacc[1] / 204800.0 - m * m;
    float a = g0[0] * rsqrtf((float)v + BNEPS);
    a0s = a; s0s = b0[0] - (float)m * a;
  }
  __syncthreads();
  float a0 = a0s, s0 = s0s;
  for (int i = t; i < 400; i += 256) xs[i] = a0 * xs[i] + s0;
  __syncthreads();
  // each group of 8 lanes handles one channel c = t>>3
  int c = t >> 3, sub = t & 7;
  const float* w = &wsm[c * 9];
  float cb = cbs[c];
  float s = 0.f, sq = 0.f;
  for (int e = sub; e < HW; e += 8) {
    int oh = e / 18, ow = e - oh * 18;
    const float* xp = &xs[oh * 20 + ow];
    float acc = cb
       + xp[0] * w[0] + xp[1] * w[1] + xp[2] * w[2]
       + xp[20] * w[3] + xp[21] * w[4] + xp[22] * w[5]
       + xp[40] * w[6] + xp[41] * w[7] + xp[42] * w[8];
    yb[(long)b * FCIN + c * HW + e] = f32_to_bf16(acc);
    s += acc; sq += acc * acc;
  }
  s += __shfl_xor(s, 1, 64); sq += __shfl_xor(sq, 1, 64);
  s += __shfl_xor(s, 2, 64); sq += __shfl_xor(sq, 2, 64);
  s += __shfl_xor(s, 4, 64); sq += __shfl_xor(sq, 4, 64);
  if (sub == 0) { ssum[c] = s; ssq[c] = sq; }
  __syncthreads();
  if (t < 32) {
    atomicAdd(&dacc[2 + t], (double)ssum[t]);
    atomicAdd(&dacc[34 + t], (double)ssq[t]);
  }
}

// K3: finalize bn1 scale/shift; conv_w L2
__global__ void k_stats1(const float* __restrict__ g1, const float* __restrict__ b1,
                         const float* __restrict__ convw,
                         float* __restrict__ a1, float* __restrict__ sh1, double* dacc) {
  int t = threadIdx.x;  // 64 threads
  if (t < 32) {
    double cnt = 512.0 * 324.0;
    double m = dacc[2 + t] / cnt, v = dacc[34 + t] / cnt - m * m;
    float a = g1[t] * rsqrtf((float)v + BNEPS);
    a1[t] = a; sh1[t] = b1[t] - (float)m * a;
  }
  float sq = 0.f;
  for (int i = t; i < 288; i += 64) { float w = convw[i]; sq += w * w; }
  for (int o = 32; o > 0; o >>= 1) sq += __shfl_down(sq, o, 64);
  if (t == 0) dacc[66] = (double)sq;
}

// K3b: fc_w -> bf16, fused sum-of-squares (L2)
__global__ __launch_bounds__(256) void k_cvt_fcw(const float* __restrict__ fcw,
                                                 unsigned short* __restrict__ fcwb,
                                                 double* dacc) {
  int g = blockIdx.x * 256 + threadIdx.x;   // 0..259199 (x8 elems); 2,073,600 total
  float sq = 0.f;
  if (g < 259200) {
    const float4* s = (const float4*)(fcw + (long)g * 8);
    float4 u = s[0], v = s[1];
    sq = u.x*u.x + u.y*u.y + u.z*u.z + u.w*u.w
       + v.x*v.x + v.y*v.y + v.z*v.z + v.w*v.w;
    ushort4 o0, o1;
    o0.x = f32_to_bf16(u.x); o0.y = f32_to_bf16(u.y);
    o0.z = f32_to_bf16(u.z); o0.w = f32_to_bf16(u.w);
    o1.x = f32_to_bf16(v.x); o1.y = f32_to_bf16(v.y);
    o1.z = f32_to_bf16(v.z); o1.w = f32_to_bf16(v.w);
    ushort4* d = (ushort4*)(fcwb + (long)g * 8);
    d[0] = o0; d[1] = o1;
  }
  __shared__ float sbuf[8];
  float tq = blk_reduce(sq, sbuf);
  if (threadIdx.x == 0) atomicAdd(&dacc[67], (double)tq);
}

// K3c: in-place bn1 + relu on yb (bf16)
__global__ __launch_bounds__(256) void k_prep(unsigned short* __restrict__ yb,
                                              const float* __restrict__ a1,
                                              const float* __restrict__ sh1) {
  __shared__ float a1s[32], sh1s[32];
  int t = threadIdx.x;
  if (t < 32) { a1s[t] = a1[t]; sh1s[t] = sh1[t]; }
  __syncthreads();
  int g = blockIdx.x * 256 + t;          // 0..663551 (x8 elems)
  int row = g / 1296;
  int c8 = (g - row * 1296) * 8;
  unsigned short* p = yb + (long)row * FCIN + c8;
  ushort4 v0 = ((ushort4*)p)[0], v1 = ((ushort4*)p)[1];
  unsigned short e[8] = {v0.x, v0.y, v0.z, v0.w, v1.x, v1.y, v1.z, v1.w};
#pragma unroll
  for (int j = 0; j < 8; j++) {
    int c = (c8 + j) / HW;
    float f = a1s[c] * bf16_to_f32(e[j]) + sh1s[c];
    e[j] = f32_to_bf16(fmaxf(f, 0.f));
  }
  v0.x = e[0]; v0.y = e[1]; v0.z = e[2]; v0.w = e[3];
  v1.x = e[4]; v1.y = e[5]; v1.z = e[6]; v1.w = e[7];
  ((ushort4*)p)[0] = v0; ((ushort4*)p)[1] = v1;
}

// K4: FC GEMM via bf16 MFMA. One wave per block; 64(b) x 64(d) tile, ksplit=27.
// Both operands straight from global (L2-resident); f32 atomic accumulate into Cfc.
__global__ __launch_bounds__(64) void k_fc_mfma(const unsigned short* __restrict__ yb,
                                                const unsigned short* __restrict__ fcwb,
                                                float* __restrict__ Cfc) {
  int wid = blockIdx.x;                 // 864 = 32 tiles * 27 ksplit
  int ks = wid >> 5, rem = wid & 31;
  int mt = rem >> 2, nt = rem & 3;
  int lane = threadIdx.x;
  int quad = lane >> 4, lr = lane & 15;
  int m0 = mt * 64, n0 = nt * 64;
  int kbeg = ks * 384;                  // 12 chunks of 32

  const unsigned short* arow[4];
  const unsigned short* brow[4];
#pragma unroll
  for (int mi = 0; mi < 4; mi++)
    arow[mi] = yb + (long)(m0 + mi * 16 + lr) * FCIN + quad * 8;
#pragma unroll
  for (int ni = 0; ni < 4; ni++) {
    int d = n0 + ni * 16 + lr;
    if (d > DD - 1) d = DD - 1;
    brow[ni] = fcwb + (long)d * FCIN + quad * 8;
  }

  floatx4 acc[4][4];
#pragma unroll
  for (int i = 0; i < 4; i++)
#pragma unroll
    for (int j = 0; j < 4; j++) acc[i][j] = (floatx4){0.f, 0.f, 0.f, 0.f};

  for (int kc = kbeg; kc < kbeg + 384; kc += 32) {
    short8 af[4], bf[4];
#pragma unroll
    for (int mi = 0; mi < 4; mi++) af[mi] = *(const short8*)(arow[mi] + kc);
#pragma unroll
    for (int ni = 0; ni < 4; ni++) bf[ni] = *(const short8*)(brow[ni] + kc);
#pragma unroll
    for (int ni = 0; ni < 4; ni++)
#pragma unroll
      for (int mi = 0; mi < 4; mi++)
        acc[mi][ni] = __builtin_amdgcn_mfma_f32_16x16x32_bf16(af[mi], bf[ni], acc[mi][ni], 0, 0, 0);
  }

#pragma unroll
  for (int ni = 0; ni < 4; ni++) {
    int d = n0 + ni * 16 + lr;
    if (d < DD) {
#pragma unroll
      for (int mi = 0; mi < 4; mi++) {
        int mbase = m0 + mi * 16 + quad * 4;
#pragma unroll
        for (int rg = 0; rg < 4; rg++)
          atomicAdd(&Cfc[(mbase + rg) * DD + d], acc[mi][ni][rg]);
      }
    }
  }
}

// K5: bn2 stats per feature -> a2/b2c
__global__ void k_bn2stats(const float* __restrict__ Cfc, const float* __restrict__ fcb,
                           const float* __restrict__ g2, const float* __restrict__ b2,
                           float* __restrict__ a2, float* __restrict__ b2c) {
  int d = blockIdx.x, lane = threadIdx.x;  // 64 threads
  float s = 0.f, sq = 0.f;
  for (int b = lane; b < NB_B; b += 64) {
    float v = Cfc[b * DD + d] + fcb[d];
    s += v; sq += v * v;
  }
  for (int o = 32; o > 0; o >>= 1) { s += __shfl_down(s, o, 64); sq += __shfl_down(sq, o, 64); }
  if (lane == 0) {
    float m = s / 512.f, v = sq / 512.f - m * m;
    float a = g2[d] * rsqrtf(v + BNEPS);
    a2[d] = a; b2c[d] = b2[d] - m * a;
  }
}

// K6: x_final = leaky_relu(bn2(fc)); write f32 (for k_pos) and bf16 padded (for MFMA)
__global__ void k_xfinal(const float* __restrict__ Cfc, const float* __restrict__ fcb,
                         const float* __restrict__ a2, const float* __restrict__ b2c,
                         float* __restrict__ xf, unsigned short* __restrict__ xfb) {
  int idx = blockIdx.x * 256 + threadIdx.x;  // 512*224
  int row = idx / KP, col = idx - row * KP;
  if (col < DD) {
    float v = Cfc[row * DD + col] + fcb[col];
    float xv = a2[col] * v + b2c[col];
    xv = xv >= 0.f ? xv : 0.01f * xv;
    xf[row * DD + col] = xv;
    xfb[idx] = f32_to_bf16(xv);
  } else {
    xfb[idx] = 0;
  }
}

// K7: sum_b scores[b, pos_t[b]]  (f32 path, high accuracy)
__global__ void k_pos(const float* __restrict__ xf, const float* __restrict__ ent,
                      const float* __restrict__ bias, const int* __restrict__ pos,
                      double* dacc) {
  int b = blockIdx.x, lane = threadIdx.x;  // 64 threads
  int e = pos[b];
  float s = 0.f;
  for (int k = lane; k < DD; k += 64) s += xf[b * DD + k] * ent[(long)e * DD + k];
  for (int o = 32; o > 0; o >>= 1) s += __shfl_down(s, o, 64);
  if (lane == 0) atomicAdd(&dacc[70], (double)(s + bias[e]));
}

// K8: scores GEMM via bf16 MFMA: D[e,b] = sum_k entb[e,k]*xfb[b,k]; fused loss epilogue.
// Block tile: 64 entities (M) x 256 batch (N); 4 waves, each 64x64 (4x4 MFMA tiles).
__global__ __launch_bounds__(256) void k_scores_mfma(
    const unsigned short* __restrict__ entb,  // [NE][KP] bf16 bits
    const unsigned short* __restrict__ xfb,   // [512][KP] bf16 bits
    const float* __restrict__ bias, double* dacc) {
  __shared__ __align__(16) unsigned short xs[256 * 40];  // 256 rows x 32 k, stride 40
  __shared__ float sbuf[8];
  int t = threadIdx.x;
  int e0 = blockIdx.x * 64;
  int n0 = blockIdx.y * 256;
  int wv = t >> 6, lane = t & 63;
  int quad = lane >> 4, lr = lane & 15;

  floatx4 acc[4][4];
#pragma unroll
  for (int i = 0; i < 4; i++)
#pragma unroll
    for (int j = 0; j < 4; j++) acc[i][j] = (floatx4){0.f, 0.f, 0.f, 0.f};

  for (int kc = 0; kc < KP; kc += 32) {  // 7 chunks
    __syncthreads();
    {  // stage xf chunk: thread t copies row n0+t, 32 bf16 (64B)
      const uint4* src = (const uint4*)(xfb + (size_t)(n0 + t) * KP + kc);
      uint4* dst = (uint4*)(xs + t * 40);
      dst[0] = src[0]; dst[1] = src[1]; dst[2] = src[2]; dst[3] = src[3];
    }
    __syncthreads();
    short8 af[4];
#pragma unroll
    for (int mi = 0; mi < 4; mi++) {
      int e = e0 + mi * 16 + lr;
      if (e >= NE) e = NE - 1;  // clamp; excluded in epilogue
      af[mi] = *(const short8*)(entb + (size_t)e * KP + kc + quad * 8);
    }
#pragma unroll
    for (int ni = 0; ni < 4; ni++) {
      short8 bf = *(const short8*)(xs + (wv * 64 + ni * 16 + lr) * 40 + quad * 8);
#pragma unroll
      for (int mi = 0; mi < 4; mi++) {
        acc[mi][ni] = __builtin_amdgcn_mfma_f32_16x16x32_bf16(af[mi], bf, acc[mi][ni], 0, 0, 0);
      }
    }
  }

  // epilogue: D row = e0 + mi*16 + quad*4 + reg, col = n0 + wv*64 + ni*16 + lr
  float sp = 0.f, ss = 0.f;
#pragma unroll
  for (int mi = 0; mi < 4; mi++) {
    int ebase = e0 + mi * 16 + quad * 4;
    float b4[4];
    if (ebase + 3 < NE) {
      float4 bv = *(const float4*)&bias[ebase];
      b4[0] = bv.x; b4[1] = bv.y; b4[2] = bv.z; b4[3] = bv.w;
    } else {
#pragma unroll
      for (int rg = 0; rg < 4; rg++) b4[rg] = (ebase + rg < NE) ? bias[ebase + rg] : 0.f;
    }
#pragma unroll
    for (int ni = 0; ni < 4; ni++) {
#pragma unroll
      for (int rg = 0; rg < 4; rg++) {
        if (ebase + rg < NE) {
          float s = acc[mi][ni][rg] + b4[rg];
          sp += fmaxf(s, 0.f) + __logf(1.f + __expf(-fabsf(s)));
          ss += s;
        }
      }
    }
  }
  float tsp = blk_reduce(sp, sbuf);
  float tss = blk_reduce(ss, sbuf);
  if (t == 0) {
    atomicAdd(&dacc[68], (double)tsp);
    atomicAdd(&dacc[69], (double)tss);
  }
}

// K9: final scalar
__global__ void k_final(const double* dacc, float* out) {
  double SP = dacc[68], S2 = dacc[69], S3 = dacc[70];
  double xy = S2 / (double)NE + 0.9 * S3;
  double kg = (SP - xy) / ((double)NB_B * (double)NE);
  double l2 = dacc[1] / 204800.0 + dacc[66] / 576.0 + dacc[67] / 400.0;
  out[0] = (float)(kg + 1e-5 * l2);
}

extern "C" void kernel_launch(void* const* d_in, const int* in_sizes, int n_in,
                              void* d_out, int out_size, void* d_ws, size_t ws_size,
                              hipStream_t stream) {
  const float* ent   = (const float*)d_in[0];
  const float* rel   = (const float*)d_in[1];
  const float* convw = (const float*)d_in[2];
  const float* convb = (const float*)d_in[3];
  const float* fcw   = (const float*)d_in[4];
  const float* fcb   = (const float*)d_in[5];
  const float* bias  = (const float*)d_in[6];
  const float* g0    = (const float*)d_in[7];
  const float* b0    = (const float*)d_in[8];
  const float* g1    = (const float*)d_in[9];
  const float* b1    = (const float*)d_in[10];
  const float* g2    = (const float*)d_in[11];
  const float* b2    = (const float*)d_in[12];
  const int*   h     = (const int*)d_in[13];
  const int*   r     = (const int*)d_in[14];
  const int*   pos   = (const int*)d_in[15];

  char* ws = (char*)d_ws;
  double* dacc = (double*)(ws + 0);                        // 8 KB
  float* a1  = (float*)(ws + 16384);                       // 32
  float* sh1 = (float*)(ws + 16384 + 128);                 // 32
  float* a2  = (float*)(ws + 16384 + 256);                 // 200
  float* b2c = (float*)(ws + 16384 + 1056);                // 200
  float* x0  = (float*)(ws + 32768);                       // 512*400 f32      (819200 B)
  float* Cfc = (float*)(ws + 851968);                      // 512*200 f32      (409600 B)
  float* xf  = (float*)(ws + 1261568);                     // 512*200 f32      (409600 B)
  unsigned short* yb   = (unsigned short*)(ws + 1671168);  // 512*10368 bf16   (10616832 B)
  unsigned short* fcwb = (unsigned short*)(ws + 12288000); // 200*10368 bf16   (4147200 B)
  unsigned short* xfb  = (unsigned short*)(ws + 16435200); // 512*224 bf16     (229376 B)
  unsigned short* entb = (unsigned short*)(ws + 16664576); // 100000*224 bf16  (44800000 B)

  hipMemsetAsync(dacc, 0, 8192, stream);
  hipMemsetAsync(Cfc, 0, 409600, stream);

  k_cvt_ent<<<21875, 256, 0, stream>>>(ent, entb);
  k_gather<<<512, 256, 0, stream>>>(ent, rel, h, r, x0, dacc);
  k_conv<<<512, 256, 0, stream>>>(x0, convw, convb, g0, b0, yb, dacc);
  k_stats1<<<1, 64, 0, stream>>>(g1, b1, convw, a1, sh1, dacc);
  k_cvt_fcw<<<1013, 256, 0, stream>>>(fcw, fcwb, dacc);
  k_prep<<<2592, 256, 0, stream>>>(yb, a1, sh1);
  k_fc_mfma<<<864, 64, 0, stream>>>(yb, fcwb, Cfc);
  k_bn2stats<<<200, 64, 0, stream>>>(Cfc, fcb, g2, b2, a2, b2c);
  k_xfinal<<<448, 256, 0, stream>>>(Cfc, fcb, a2, b2c, xf, xfb);
  k_pos<<<512, 64, 0, stream>>>(xf, ent, bias, pos, dacc);
  k_scores_mfma<<<dim3(1563, 2), 256, 0, stream>>>(entb, xfb, bias, dacc);
  k_final<<<1, 1, 0, stream>>>(dacc, (float*)d_out);
}

// Round 4
// 328.864 us; speedup vs baseline: 2.5536x; 1.1221x over previous
//
#include <hip/hip_runtime.h>
#include <math.h>

#define NB_B 512
#define NE 100000
#define DD 200
#define CC 32
#define FCIN 10368   // 32*18*18
#define HW 324       // 18*18
#define BNEPS 1e-5f
#define KP 224       // scores K padded to multiple of 32 for MFMA
#define NTILE 1563   // ceil(NE/64)

typedef __attribute__((ext_vector_type(8))) short short8;   // 8 bf16 = 4 VGPRs
typedef __attribute__((ext_vector_type(4))) float floatx4;  // MFMA acc

// dacc (double) slots:
// 0: bn0 sum, 1: bn0 sumsq (also l2 for h_e+r_e)
// 2..33: bn1 per-channel sum, 34..65: bn1 per-channel sumsq
// 66: conv_w sumsq, 67: fc_w sumsq
// 68: softplus sum, 69: scores sum, 70: pos-scores sum

static __device__ __forceinline__ float blk_reduce(float v, volatile float* sbuf) {
  for (int o = 32; o > 0; o >>= 1) v += __shfl_down(v, o, 64);
  int lane = threadIdx.x & 63, wid = threadIdx.x >> 6;
  if (lane == 0) sbuf[wid] = v;
  __syncthreads();
  float r = 0.f;
  int nw = (blockDim.x + 63) >> 6;
  if ((int)threadIdx.x < nw) r = sbuf[threadIdx.x];
  if (threadIdx.x < 64) {
    for (int o = 32; o > 0; o >>= 1) r += __shfl_down(r, o, 64);
  }
  __syncthreads();
  return r;  // valid on thread 0
}

static __device__ __forceinline__ unsigned short f32_to_bf16(float f) {
  unsigned int u = __float_as_uint(f);
  u += 0x7fffu + ((u >> 16) & 1u);  // round-to-nearest-even
  return (unsigned short)(u >> 16);
}
static __device__ __forceinline__ float bf16_to_f32(unsigned short b) {
  return __uint_as_float(((unsigned int)b) << 16);
}

// K1: gather h/r embeddings -> x0 [512 x 400]; bn0 sum/sumsq (sumsq doubles as embed L2)
__global__ void k_gather(const float* __restrict__ ent, const float* __restrict__ rel,
                         const int* __restrict__ h, const int* __restrict__ r,
                         float* __restrict__ x0, double* dacc) {
  int b = blockIdx.x;
  int hi = h[b], ri = r[b];
  float s = 0.f, sq = 0.f;
  for (int i = threadIdx.x; i < 400; i += blockDim.x) {
    float v = (i < 200) ? ent[(long)hi * DD + i] : rel[(long)ri * DD + (i - 200)];
    x0[b * 400 + i] = v;
    s += v; sq += v * v;
  }
  __shared__ float sbuf[8];
  float ts = blk_reduce(s, sbuf);
  float tq = blk_reduce(sq, sbuf);
  if (threadIdx.x == 0) {
    atomicAdd(&dacc[0], (double)ts);
    atomicAdd(&dacc[1], (double)tq);
  }
}

// K1b: fused converts. Blocks [0,21875): entity_w f32 -> bf16 padded 200->224.
// Blocks [21875, 22888): fc_w f32 -> bf16 + sumsq (L2 term).
__global__ __launch_bounds__(256) void k_cvt(const float* __restrict__ ent,
                                             unsigned short* __restrict__ entb,
                                             const float* __restrict__ fcw,
                                             unsigned short* __restrict__ fcwb,
                                             double* dacc) {
  if (blockIdx.x < 21875) {
    int i4 = blockIdx.x * 256 + threadIdx.x;   // 0 .. 5,599,999  (100000*56)
    int row = i4 / 56;
    int c4 = (i4 - row * 56) * 4;
    ushort4 o;
    if (c4 < 200) {
      const float4 v = *(const float4*)&ent[(long)row * DD + c4];
      o.x = f32_to_bf16(v.x); o.y = f32_to_bf16(v.y);
      o.z = f32_to_bf16(v.z); o.w = f32_to_bf16(v.w);
    } else {
      o.x = 0; o.y = 0; o.z = 0; o.w = 0;
    }
    *(ushort4*)&entb[(long)row * KP + c4] = o;
  } else {
    int g = (blockIdx.x - 21875) * 256 + threadIdx.x;   // x8 elems; 2,073,600 total
    float sq = 0.f;
    if (g < 259200) {
      const float4* s = (const float4*)(fcw + (long)g * 8);
      float4 u = s[0], v = s[1];
      sq = u.x*u.x + u.y*u.y + u.z*u.z + u.w*u.w
         + v.x*v.x + v.y*v.y + v.z*v.z + v.w*v.w;
      ushort4 o0, o1;
      o0.x = f32_to_bf16(u.x); o0.y = f32_to_bf16(u.y);
      o0.z = f32_to_bf16(u.z); o0.w = f32_to_bf16(u.w);
      o1.x = f32_to_bf16(v.x); o1.y = f32_to_bf16(v.y);
      o1.z = f32_to_bf16(v.z); o1.w = f32_to_bf16(v.w);
      ushort4* d = (ushort4*)(fcwb + (long)g * 8);
      d[0] = o0; d[1] = o1;
    }
    __shared__ float sbuf[8];
    float tq = blk_reduce(sq, sbuf);
    if (threadIdx.x == 0) atomicAdd(&dacc[67], (double)tq);
  }
}

// K2: bn0 + conv3x3 + conv_b -> yb bf16 [512 x 10368] (pre-bn1); bn1 stats (f32)
__global__ __launch_bounds__(256) void k_conv(const float* __restrict__ x0,
                       const float* __restrict__ convw, const float* __restrict__ convb,
                       const float* __restrict__ g0, const float* __restrict__ b0,
                       unsigned short* __restrict__ yb, double* dacc) {
  __shared__ float xs[400], wsm[288], cbs[32], ssum[32], ssq[32];
  __shared__ float a0s, s0s;
  int b = blockIdx.x, t = threadIdx.x;
  for (int i = t; i < 400; i += 256) xs[i] = x0[b * 400 + i];
  for (int i = t; i < 288; i += 256) wsm[i] = convw[i];
  if (t < 32) cbs[t] = convb[t];
  if (t == 0) {
    double m = dacc[0] / 204800.0;
    double v = dacc[1] / 204800.0 - m * m;
    float a = g0[0] * rsqrtf((float)v + BNEPS);
    a0s = a; s0s = b0[0] - (float)m * a;
  }
  __syncthreads();
  float a0 = a0s, s0 = s0s;
  for (int i = t; i < 400; i += 256) xs[i] = a0 * xs[i] + s0;
  __syncthreads();
  int c = t >> 3, sub = t & 7;
  const float* w = &wsm[c * 9];
  float cb = cbs[c];
  float s = 0.f, sq = 0.f;
  for (int e = sub; e < HW; e += 8) {
    int oh = e / 18, ow = e - oh * 18;
    const float* xp = &xs[oh * 20 + ow];
    float acc = cb
       + xp[0] * w[0] + xp[1] * w[1] + xp[2] * w[2]
       + xp[20] * w[3] + xp[21] * w[4] + xp[22] * w[5]
       + xp[40] * w[6] + xp[41] * w[7] + xp[42] * w[8];
    yb[(long)b * FCIN + c * HW + e] = f32_to_bf16(acc);
    s += acc; sq += acc * acc;
  }
  s += __shfl_xor(s, 1, 64); sq += __shfl_xor(sq, 1, 64);
  s += __shfl_xor(s, 2, 64); sq += __shfl_xor(sq, 2, 64);
  s += __shfl_xor(s, 4, 64); sq += __shfl_xor(sq, 4, 64);
  if (sub == 0) { ssum[c] = s; ssq[c] = sq; }
  __syncthreads();
  if (t < 32) {
    atomicAdd(&dacc[2 + t], (double)ssum[t]);
    atomicAdd(&dacc[34 + t], (double)ssq[t]);
  }
}

// K3: finalize bn1 scale/shift; conv_w L2
__global__ void k_stats1(const float* __restrict__ g1, const float* __restrict__ b1,
                         const float* __restrict__ convw,
                         float* __restrict__ a1, float* __restrict__ sh1, double* dacc) {
  int t = threadIdx.x;  // 64 threads
  if (t < 32) {
    double cnt = 512.0 * 324.0;
    double m = dacc[2 + t] / cnt, v = dacc[34 + t] / cnt - m * m;
    float a = g1[t] * rsqrtf((float)v + BNEPS);
    a1[t] = a; sh1[t] = b1[t] - (float)m * a;
  }
  float sq = 0.f;
  for (int i = t; i < 288; i += 64) { float w = convw[i]; sq += w * w; }
  for (int o = 32; o > 0; o >>= 1) sq += __shfl_down(sq, o, 64);
  if (t == 0) dacc[66] = (double)sq;
}

// K3c: in-place bn1 + relu on yb (bf16)
__global__ __launch_bounds__(256) void k_prep(unsigned short* __restrict__ yb,
                                              const float* __restrict__ a1,
                                              const float* __restrict__ sh1) {
  __shared__ float a1s[32], sh1s[32];
  int t = threadIdx.x;
  if (t < 32) { a1s[t] = a1[t]; sh1s[t] = sh1[t]; }
  __syncthreads();
  int g = blockIdx.x * 256 + t;          // 0..663551 (x8 elems)
  int row = g / 1296;
  int c8 = (g - row * 1296) * 8;
  unsigned short* p = yb + (long)row * FCIN + c8;
  ushort4 v0 = ((ushort4*)p)[0], v1 = ((ushort4*)p)[1];
  unsigned short e[8] = {v0.x, v0.y, v0.z, v0.w, v1.x, v1.y, v1.z, v1.w};
#pragma unroll
  for (int j = 0; j < 8; j++) {
    int c = (c8 + j) / HW;
    float f = a1s[c] * bf16_to_f32(e[j]) + sh1s[c];
    e[j] = f32_to_bf16(fmaxf(f, 0.f));
  }
  v0.x = e[0]; v0.y = e[1]; v0.z = e[2]; v0.w = e[3];
  v1.x = e[4]; v1.y = e[5]; v1.z = e[6]; v1.w = e[7];
  ((ushort4*)p)[0] = v0; ((ushort4*)p)[1] = v1;
}

// K4: FC GEMM via bf16 MFMA. One wave per block; 64(b) x 64(d) tile, ksplit=54,
// software-pipelined loads; f32 atomic accumulate into Cfc.
__global__ __launch_bounds__(64) void k_fc_mfma(const unsigned short* __restrict__ yb,
                                                const unsigned short* __restrict__ fcwb,
                                                float* __restrict__ Cfc) {
  int wid = blockIdx.x;                 // 1728 = 32 tiles * 54 ksplit
  int ks = wid >> 5, rem = wid & 31;
  int mt = rem >> 2, nt = rem & 3;
  int lane = threadIdx.x;
  int quad = lane >> 4, lr = lane & 15;
  int m0 = mt * 64, n0 = nt * 64;
  int kbeg = ks * 192;                  // 6 chunks of 32

  const unsigned short* arow[4];
  const unsigned short* brow[4];
#pragma unroll
  for (int mi = 0; mi < 4; mi++)
    arow[mi] = yb + (long)(m0 + mi * 16 + lr) * FCIN + quad * 8 + kbeg;
#pragma unroll
  for (int ni = 0; ni < 4; ni++) {
    int d = n0 + ni * 16 + lr;
    if (d > DD - 1) d = DD - 1;
    brow[ni] = fcwb + (long)d * FCIN + quad * 8 + kbeg;
  }

  floatx4 acc[4][4];
#pragma unroll
  for (int i = 0; i < 4; i++)
#pragma unroll
    for (int j = 0; j < 4; j++) acc[i][j] = (floatx4){0.f, 0.f, 0.f, 0.f};

  short8 acur[4], bcur[4], anxt[4], bnxt[4];
#pragma unroll
  for (int mi = 0; mi < 4; mi++) acur[mi] = *(const short8*)(arow[mi]);
#pragma unroll
  for (int ni = 0; ni < 4; ni++) bcur[ni] = *(const short8*)(brow[ni]);

#pragma unroll
  for (int c = 0; c < 6; c++) {
    if (c < 5) {
#pragma unroll
      for (int mi = 0; mi < 4; mi++) anxt[mi] = *(const short8*)(arow[mi] + (c + 1) * 32);
#pragma unroll
      for (int ni = 0; ni < 4; ni++) bnxt[ni] = *(const short8*)(brow[ni] + (c + 1) * 32);
    }
#pragma unroll
    for (int ni = 0; ni < 4; ni++)
#pragma unroll
      for (int mi = 0; mi < 4; mi++)
        acc[mi][ni] = __builtin_amdgcn_mfma_f32_16x16x32_bf16(acur[mi], bcur[ni], acc[mi][ni], 0, 0, 0);
#pragma unroll
    for (int mi = 0; mi < 4; mi++) acur[mi] = anxt[mi];
#pragma unroll
    for (int ni = 0; ni < 4; ni++) bcur[ni] = bnxt[ni];
  }

#pragma unroll
  for (int ni = 0; ni < 4; ni++) {
    int d = n0 + ni * 16 + lr;
    if (d < DD) {
#pragma unroll
      for (int mi = 0; mi < 4; mi++) {
        int mbase = m0 + mi * 16 + quad * 4;
#pragma unroll
        for (int rg = 0; rg < 4; rg++)
          atomicAdd(&Cfc[(mbase + rg) * DD + d], acc[mi][ni][rg]);
      }
    }
  }
}

// K5: bn2 stats per feature -> a2/b2c
__global__ void k_bn2stats(const float* __restrict__ Cfc, const float* __restrict__ fcb,
                           const float* __restrict__ g2, const float* __restrict__ b2,
                           float* __restrict__ a2, float* __restrict__ b2c) {
  int d = blockIdx.x, lane = threadIdx.x;  // 64 threads
  float s = 0.f, sq = 0.f;
  for (int b = lane; b < NB_B; b += 64) {
    float v = Cfc[b * DD + d] + fcb[d];
    s += v; sq += v * v;
  }
  for (int o = 32; o > 0; o >>= 1) { s += __shfl_down(s, o, 64); sq += __shfl_down(sq, o, 64); }
  if (lane == 0) {
    float m = s / 512.f, v = sq / 512.f - m * m;
    float a = g2[d] * rsqrtf(v + BNEPS);
    a2[d] = a; b2c[d] = b2[d] - m * a;
  }
}

// K6: x_final row: leaky_relu(bn2(fc)) -> xf f32 + xfb bf16(padded); fused pos-score
__global__ __launch_bounds__(256) void k_xfinal(const float* __restrict__ Cfc,
                         const float* __restrict__ fcb,
                         const float* __restrict__ a2, const float* __restrict__ b2c,
                         const float* __restrict__ ent, const float* __restrict__ bias,
                         const int* __restrict__ pos,
                         float* __restrict__ xf, unsigned short* __restrict__ xfb,
                         double* dacc) {
  __shared__ float xs[224];
  __shared__ float sbuf[8];
  int b = blockIdx.x, t = threadIdx.x;
  if (t < KP) {
    float xv = 0.f;
    if (t < DD) {
      float v = Cfc[b * DD + t] + fcb[t];
      xv = a2[t] * v + b2c[t];
      xv = xv >= 0.f ? xv : 0.01f * xv;
      xf[b * DD + t] = xv;
    }
    xfb[b * KP + t] = f32_to_bf16(xv);
    xs[t] = xv;
  }
  __syncthreads();
  int e = pos[b];
  float s = (t < DD) ? xs[t] * ent[(long)e * DD + t] : 0.f;
  float ts = blk_reduce(s, sbuf);
  if (t == 0) atomicAdd(&dacc[70], (double)(ts + bias[e]));
}

// K8: scores GEMM, register-resident A (xf), streamed B (entities), no LDS/barriers.
// 512 threads = 8 waves; wave w owns batch rows [w*64, w*64+64); loop over 64-ent tiles.
__global__ __launch_bounds__(512, 2) void k_scores2(
    const unsigned short* __restrict__ entb,  // [NE][KP] bf16 bits
    const unsigned short* __restrict__ xfb,   // [512][KP] bf16 bits
    const float* __restrict__ bias, double* dacc) {
  __shared__ float sbuf[8];
  int t = threadIdx.x;
  int wv = t >> 6, lane = t & 63;
  int quad = lane >> 4, lr = lane & 15;

  // A fragments: xf rows, held in registers for the whole kernel (112 VGPRs)
  short8 af[4][7];
#pragma unroll
  for (int mi = 0; mi < 4; mi++) {
    const unsigned short* ap = xfb + (size_t)(wv * 64 + mi * 16 + lr) * KP + quad * 8;
#pragma unroll
    for (int kc = 0; kc < 7; kc++) af[mi][kc] = *(const short8*)(ap + kc * 32);
  }

  float sp = 0.f, ss = 0.f;
  for (int tile = blockIdx.x; tile < NTILE; tile += gridDim.x) {
    int e0 = tile * 64;
    const unsigned short* bp[4];
    int eidx[4];
#pragma unroll
    for (int ni = 0; ni < 4; ni++) {
      int e = e0 + ni * 16 + lr;
      eidx[ni] = e;
      if (e > NE - 1) e = NE - 1;
      bp[ni] = entb + (size_t)e * KP + quad * 8;
    }
    floatx4 acc[4][4];
#pragma unroll
    for (int i = 0; i < 4; i++)
#pragma unroll
      for (int j = 0; j < 4; j++) acc[i][j] = (floatx4){0.f, 0.f, 0.f, 0.f};

    short8 bcur[4], bnxt[4];
#pragma unroll
    for (int ni = 0; ni < 4; ni++) bcur[ni] = *(const short8*)(bp[ni]);
#pragma unroll
    for (int kc = 0; kc < 7; kc++) {
      if (kc < 6) {
#pragma unroll
        for (int ni = 0; ni < 4; ni++) bnxt[ni] = *(const short8*)(bp[ni] + (kc + 1) * 32);
      }
#pragma unroll
      for (int ni = 0; ni < 4; ni++)
#pragma unroll
        for (int mi = 0; mi < 4; mi++)
          acc[mi][ni] = __builtin_amdgcn_mfma_f32_16x16x32_bf16(af[mi][kc], bcur[ni], acc[mi][ni], 0, 0, 0);
#pragma unroll
      for (int ni = 0; ni < 4; ni++) bcur[ni] = bnxt[ni];
    }
    // epilogue: D row(batch) = wv*64 + mi*16 + quad*4 + rg, col(entity) = e0 + ni*16 + lr
#pragma unroll
    for (int ni = 0; ni < 4; ni++) {
      if (eidx[ni] < NE) {
        float be = bias[eidx[ni]];
#pragma unroll
        for (int mi = 0; mi < 4; mi++) {
#pragma unroll
          for (int rg = 0; rg < 4; rg++) {
            float s = acc[mi][ni][rg] + be;
            sp += fmaxf(s, 0.f) + __logf(1.f + __expf(-fabsf(s)));
            ss += s;
          }
        }
      }
    }
  }
  float tsp = blk_reduce(sp, sbuf);
  float tss = blk_reduce(ss, sbuf);
  if (t == 0) {
    atomicAdd(&dacc[68], (double)tsp);
    atomicAdd(&dacc[69], (double)tss);
  }
}

// K9: final scalar
__global__ void k_final(const double* dacc, float* out) {
  double SP = dacc[68], S2 = dacc[69], S3 = dacc[70];
  double xy = S2 / (double)NE + 0.9 * S3;
  double kg = (SP - xy) / ((double)NB_B * (double)NE);
  double l2 = dacc[1] / 204800.0 + dacc[66] / 576.0 + dacc[67] / 400.0;
  out[0] = (float)(kg + 1e-5 * l2);
}

extern "C" void kernel_launch(void* const* d_in, const int* in_sizes, int n_in,
                              void* d_out, int out_size, void* d_ws, size_t ws_size,
                              hipStream_t stream) {
  const float* ent   = (const float*)d_in[0];
  const float* rel   = (const float*)d_in[1];
  const float* convw = (const float*)d_in[2];
  const float* convb = (const float*)d_in[3];
  const float* fcw   = (const float*)d_in[4];
  const float* fcb   = (const float*)d_in[5];
  const float* bias  = (const float*)d_in[6];
  const float* g0    = (const float*)d_in[7];
  const float* b0    = (const float*)d_in[8];
  const float* g1    = (const float*)d_in[9];
  const float* b1    = (const float*)d_in[10];
  const float* g2    = (const float*)d_in[11];
  const float* b2    = (const float*)d_in[12];
  const int*   h     = (const int*)d_in[13];
  const int*   r     = (const int*)d_in[14];
  const int*   pos   = (const int*)d_in[15];

  char* ws = (char*)d_ws;
  double* dacc = (double*)(ws + 0);                        // 8 KB
  float* a1  = (float*)(ws + 16384);                       // 32
  float* sh1 = (float*)(ws + 16384 + 128);                 // 32
  float* a2  = (float*)(ws + 16384 + 256);                 // 200
  float* b2c = (float*)(ws + 16384 + 1056);                // 200
  float* x0  = (float*)(ws + 32768);                       // 512*400 f32      (819200 B)
  float* Cfc = (float*)(ws + 851968);                      // 512*200 f32      (409600 B)
  float* xf  = (float*)(ws + 1261568);                     // 512*200 f32      (409600 B)
  unsigned short* yb   = (unsigned short*)(ws + 1671168);  // 512*10368 bf16   (10616832 B)
  unsigned short* fcwb = (unsigned short*)(ws + 12288000); // 200*10368 bf16   (4147200 B)
  unsigned short* xfb  = (unsigned short*)(ws + 16435200); // 512*224 bf16     (229376 B)
  unsigned short* entb = (unsigned short*)(ws + 16664576); // 100000*224 bf16  (44800000 B)

  hipMemsetAsync(dacc, 0, 8192, stream);
  hipMemsetAsync(Cfc, 0, 409600, stream);

  k_cvt<<<22888, 256, 0, stream>>>(ent, entb, fcw, fcwb, dacc);
  k_gather<<<512, 256, 0, stream>>>(ent, rel, h, r, x0, dacc);
  k_conv<<<512, 256, 0, stream>>>(x0, convw, convb, g0, b0, yb, dacc);
  k_stats1<<<1, 64, 0, stream>>>(g1, b1, convw, a1, sh1, dacc);
  k_prep<<<2592, 256, 0, stream>>>(yb, a1, sh1);
  k_fc_mfma<<<1728, 64, 0, stream>>>(yb, fcwb, Cfc);
  k_bn2stats<<<200, 64, 0, stream>>>(Cfc, fcb, g2, b2, a2, b2c);
  k_xfinal<<<512, 256, 0, stream>>>(Cfc, fcb, a2, b2c, ent, bias, pos, xf, xfb, dacc);
  k_scores2<<<256, 512, 0, stream>>>(entb, xfb, bias, dacc);
  k_final<<<1, 1, 0, stream>>>(dacc, (float*)d_out);
}